// Round 9
// baseline (487.051 us; speedup 1.0000x reference)
//
#include <hip/hip_runtime.h>
#include <cstdint>
#include <cstddef>

typedef __attribute__((ext_vector_type(8))) short short8;
typedef __attribute__((ext_vector_type(8))) unsigned short ushort8;
typedef __attribute__((ext_vector_type(4))) float f32x4;

#define EPSV 1e-5f
#define NEDGE 1048576
#define EPG 1024
#define CNTF 65536.0f
#define REP 32
#define GRID 1024

__device__ __forceinline__ ushort f2bf(float f) {
  uint u = __float_as_uint(f);
  return (ushort)((u + 0x7FFFu + ((u >> 16) & 1u)) >> 16);
}
__device__ __forceinline__ float bf2f(ushort u) {
  return __uint_as_float((uint)u << 16);
}

// manual grid barrier (counters zeroed by pre-launch memset). All GRID blocks
// are co-resident by construction: LDS 36,384B <= 40KB and
// __launch_bounds__(256,4) => 4 blocks/CU x 256 CUs = 1024.
__device__ __forceinline__ void gbar(int* bar, int nb) {
  __syncthreads();
  if (threadIdx.x == 0) {
    __threadfence();
    __hip_atomic_fetch_add(bar, 1, __ATOMIC_ACQ_REL, __HIP_MEMORY_SCOPE_AGENT);
    while (__hip_atomic_load(bar, __ATOMIC_ACQUIRE, __HIP_MEMORY_SCOPE_AGENT) < nb)
      __builtin_amdgcn_s_sleep(1);
    __threadfence();
  }
  __syncthreads();
}

// ---- shared-memory union (max = SmemConv = 36384 B -> 4 blocks/CU)
struct SmemEdge {
  float xs[64];
  float aggT[4][5][72];
  float aggC[64][8];
  float w1s[8], b1s[4];
  float w2s[256], b2s[64];
  float rs[4][64], rss[4][64];
};
struct SmemPrep { ushort T[64][72]; };
struct SmemConv {
  ushort As[64][200];
  ushort Yt[66][72];
  float aco[64], bco[64], cbs[64];
  float ldsS[64], ldsSS[64];
};
struct SmemMlp1 {
  float a3s[64], b3s[64];
  ushort Ys[64][72];
  ushort Ws[64][72];
};

// ---------------------------------------------------------------------------
// conv stage, one graph per block (proven R6 shape).
// ---------------------------------------------------------------------------
__device__ __forceinline__ void conv_stage(
    SmemConv* S, const int g, const int tid,
    const ushort* __restrict__ in, const float* __restrict__ stats_in,
    const float* __restrict__ gamma, const float* __restrict__ beta,
    const ushort* __restrict__ cwt, const float* __restrict__ cb,
    ushort* __restrict__ out, float* __restrict__ stats_out)
{
  if (tid < 64) {
    float sm = 0.f, sq = 0.f;
#pragma unroll 8
    for (int r = 0; r < REP; ++r) {
      sm += stats_in[(r << 7) + tid];
      sq += stats_in[(r << 7) + 64 + tid];
    }
    const float mean = sm * (1.0f / CNTF);
    const float var = sq * (1.0f / CNTF) - mean * mean;
    const float a = gamma[tid] * rsqrtf(var + EPSV);
    S->aco[tid] = a;
    S->bco[tid] = beta[tid] - mean * a;
    S->cbs[tid] = cb[tid];
    S->Yt[0][tid] = 0;
    S->Yt[65][tid] = 0;
  }
  {
    const ushort8* gw = (const ushort8*)cwt;
#pragma unroll
    for (int i = 0; i < 6; ++i) {
      const int e8 = (i << 8) + tid;
      const int o = e8 / 24, k8 = (e8 - o * 24) << 3;
      *(ushort8*)&S->As[o][k8] = gw[e8];
    }
  }
  __syncthreads();

  const size_t base = (size_t)g << 12;
  {
    const int lr = tid >> 2, p = (tid & 3) << 4;
    const ushort8 r0 = *(const ushort8*)&in[base + (lr << 6) + p];
    const ushort8 r1 = *(const ushort8*)&in[base + (lr << 6) + p + 8];
    ushort tmp[16];
#pragma unroll
    for (int j = 0; j < 8; ++j)
      tmp[j] = f2bf(fmaxf(fmaf(S->aco[p + j], bf2f(r0[j]), S->bco[p + j]), 0.f));
#pragma unroll
    for (int j = 0; j < 8; ++j)
      tmp[8 + j] = f2bf(fmaxf(fmaf(S->aco[p + 8 + j], bf2f(r1[j]), S->bco[p + 8 + j]), 0.f));
    *(ushort8*)&S->Yt[lr + 1][p] = *(ushort8*)&tmp[0];
    *(ushort8*)&S->Yt[lr + 1][p + 8] = *(ushort8*)&tmp[8];
  }
  __syncthreads();

  const int lane = tid & 63, w = tid >> 6;
  const int lm = lane & 15, q = lane >> 4;
  f32x4 acc[4];
#pragma unroll
  for (int nt = 0; nt < 4; ++nt) acc[nt] = (f32x4){0.f, 0.f, 0.f, 0.f};
#pragma unroll
  for (int kk = 0; kk < 3; ++kk) {
#pragma unroll
    for (int ks = 0; ks < 2; ++ks) {
      const short8 af = *(const short8*)&S->As[(w << 4) + lm][(kk << 6) + (ks << 5) + (q << 3)];
#pragma unroll
      for (int nt = 0; nt < 4; ++nt) {
        const short8 bfr = *(const short8*)&S->Yt[(nt << 4) + lm + kk][(ks << 5) + (q << 3)];
        acc[nt] = __builtin_amdgcn_mfma_f32_16x16x32_bf16(af, bfr, acc[nt], 0, 0, 0);
      }
    }
  }

  const int obase = (w << 4) + (q << 2);
  const float4 cb4 = *(const float4*)&S->cbs[obase];
  float s[4] = {0.f, 0.f, 0.f, 0.f}, ss[4] = {0.f, 0.f, 0.f, 0.f};
#pragma unroll
  for (int nt = 0; nt < 4; ++nt) {
    const int l = (nt << 4) + lm;
    float4 v = make_float4(acc[nt][0] + cb4.x, acc[nt][1] + cb4.y,
                           acc[nt][2] + cb4.z, acc[nt][3] + cb4.w);
    *(ushort4*)&out[base + (l << 6) + obase] =
        make_ushort4(f2bf(v.x), f2bf(v.y), f2bf(v.z), f2bf(v.w));
    s[0] += v.x; ss[0] += v.x * v.x;
    s[1] += v.y; ss[1] += v.y * v.y;
    s[2] += v.z; ss[2] += v.z * v.z;
    s[3] += v.w; ss[3] += v.w * v.w;
  }
#pragma unroll
  for (int i = 0; i < 4; ++i) {
#pragma unroll
    for (int off = 1; off < 16; off <<= 1) {
      s[i] += __shfl_xor(s[i], off);
      ss[i] += __shfl_xor(ss[i], off);
    }
    if (lm == 0) { S->ldsS[obase + i] = s[i]; S->ldsSS[obase + i] = ss[i]; }
  }
  __syncthreads();
  if (tid < 64) {
    float* dst = stats_out + ((g & (REP - 1)) << 7);
    atomicAdd(&dst[tid], S->ldsS[tid]);
    atomicAdd(&dst[64 + tid], S->ldsSS[tid]);
  }
}

// ---------------------------------------------------------------------------
// k_fused: prep+edge | conv2 | conv3 | mlp1, 1024 blocks with grid barriers.
// ---------------------------------------------------------------------------
__global__ __launch_bounds__(256, 4) void k_fused(
    const float* __restrict__ x, const int* __restrict__ ei,
    const float* __restrict__ w1, const float* __restrict__ b1,
    const float* __restrict__ w2, const float* __restrict__ b2,
    const float* __restrict__ c2w, const float* __restrict__ c3w,
    const float* __restrict__ g1, const float* __restrict__ be1,
    const float* __restrict__ c2b,
    const float* __restrict__ g2, const float* __restrict__ be2,
    const float* __restrict__ c3b,
    const float* __restrict__ g3, const float* __restrict__ be3,
    const float* __restrict__ wm1, const float* __restrict__ wm2,
    const float* __restrict__ wm3, const float* __restrict__ wp,
    ushort* __restrict__ ubuf0, ushort* __restrict__ ubuf1,
    float* __restrict__ h1part, ushort* __restrict__ wbf1t,
    ushort* __restrict__ wbf2t, ushort* __restrict__ wbf3t,
    ushort* __restrict__ wptbf, float* __restrict__ stats,
    ushort* __restrict__ cwt2, ushort* __restrict__ cwt3,
    int* __restrict__ bar)
{
  __shared__ __align__(16) char smem[sizeof(SmemConv)];
  const int tid = threadIdx.x;
  const int b = blockIdx.x;
  float* stats1 = stats;
  float* stats2 = stats + REP * 128;
  float* stats3 = stats + 2 * REP * 128;

  // ======== S0a: weight prep (disjoint block ranges) ========
  if (b < 256) {           // wm1 -> wbf1t chunk-major (row-perm k' = l*64+c)
    SmemPrep* P = (SmemPrep*)smem;
    const int kc = b >> 2, n0 = (b & 3) << 6;
    const int kk = tid >> 2, np = (tid & 3) << 4;
    const float* srow = wm1 + (((size_t)(kk << 6) + kc) << 8) + n0 + np;
#pragma unroll
    for (int i = 0; i < 4; ++i) {
      const float4 v = *(const float4*)(srow + (i << 2));
      const int n = np + (i << 2);
      P->T[n + 0][kk] = f2bf(v.x); P->T[n + 1][kk] = f2bf(v.y);
      P->T[n + 2][kk] = f2bf(v.z); P->T[n + 3][kk] = f2bf(v.w);
    }
    __syncthreads();
    ushort* dst = wbf1t + ((size_t)kc << 14) + (n0 << 6);
    const int nl = tid >> 2, qk = (tid & 3) << 4;
    *(ushort8*)(dst + (nl << 6) + qk) = *(ushort8*)&P->T[nl][qk];
    *(ushort8*)(dst + (nl << 6) + qk + 8) = *(ushort8*)&P->T[nl][qk + 8];
    __syncthreads();       // done with P->T before edge reuses LDS
  } else if (b < 320) {    // wm2/wm3 -> chunk-major
    const int base = (((b - 256) << 8) + tid) << 3;
    const int m = base >> 16;
    const int rem = base & 65535;
    const int kc = rem >> 14, within = rem & 16383;
    const int n = within >> 6, kk0 = within & 63;
    const float* src = m ? wm3 : wm2;
    ushort* dst = m ? wbf3t : wbf2t;
    ushort tmp[8];
#pragma unroll
    for (int j = 0; j < 8; ++j)
      tmp[j] = f2bf(src[(((kc << 6) | (kk0 + j)) << 8) + n]);
    *(ushort8*)&dst[rem] = *(ushort8*)&tmp[0];
  } else if (b == 320) {   // wp -> wp^T
    const int a = tid & 15, k0 = (tid >> 4) << 4;
    ushort tmp[16];
#pragma unroll
    for (int j = 0; j < 16; ++j) tmp[j] = f2bf(wp[((k0 + j) << 4) + a]);
    *(ushort8*)&wptbf[(a << 8) + k0] = *(ushort8*)&tmp[0];
    *(ushort8*)&wptbf[(a << 8) + k0 + 8] = *(ushort8*)&tmp[8];
  } else if (b < 417) {    // conv weights -> cwt (d_out scratch)
    const int flat = (b - 321) * 256 + tid;
    const int m = flat >= 12288;
    const int idx = flat - (m ? 12288 : 0);
    const float* src = m ? c3w : c2w;
    ushort* dst = m ? cwt3 : cwt2;
    const int o = idx / 192, rem2 = idx - o * 192;
    const int kk = rem2 >> 6, c = rem2 & 63;
    dst[idx] = f2bf(src[o * 192 + c * 3 + kk]);
  }

  // ======== S0b: EdgeConv, graph b (proven shape) ========
  {
    SmemEdge* S = (SmemEdge*)smem;
    const int w = tid >> 6;
    if (tid < 8) S->w1s[tid] = w1[tid];
    if (tid < 4) S->b1s[tid] = b1[tid];
    if (tid < 64) { S->xs[tid] = x[(b << 6) + tid]; S->b2s[tid] = b2[tid]; }
    S->w2s[tid] = w2[tid];
    for (int i = tid; i < 1440; i += 256) ((float*)S->aggT)[i] = 0.f;
    __syncthreads();

    const int e0 = b * EPG;
    const int4 s4 = ((const int4*)(ei + e0))[tid];
    const int4 d4 = ((const int4*)(ei + NEDGE + e0))[tid];
    float* agw = &S->aggT[w][0][0];
    const int sls[4] = {s4.x & 63, s4.y & 63, s4.z & 63, s4.w & 63};
    const int dls[4] = {d4.x & 63, d4.y & 63, d4.z & 63, d4.w & 63};
#pragma unroll
    for (int e = 0; e < 4; ++e) {
      const int dl = dls[e];
      const float xi = S->xs[dl];
      const float dx = S->xs[sls[e]] - xi;
#pragma unroll
      for (int j = 0; j < 4; ++j) {
        float h = fmaxf(fmaf(xi, S->w1s[j], fmaf(dx, S->w1s[4 + j], S->b1s[j])), 0.f);
        atomicAdd(&agw[j * 72 + dl], h);
      }
      atomicAdd(&agw[4 * 72 + dl], 1.0f);
    }
    __syncthreads();

    if (tid < 64) {
      const int n = tid;
      const float a0 = S->aggT[0][0][n] + S->aggT[1][0][n] + S->aggT[2][0][n] + S->aggT[3][0][n];
      const float a1 = S->aggT[0][1][n] + S->aggT[1][1][n] + S->aggT[2][1][n] + S->aggT[3][1][n];
      const float a2 = S->aggT[0][2][n] + S->aggT[1][2][n] + S->aggT[2][2][n] + S->aggT[3][2][n];
      const float a3v = S->aggT[0][3][n] + S->aggT[1][3][n] + S->aggT[2][3][n] + S->aggT[3][3][n];
      const float dg = S->aggT[0][4][n] + S->aggT[1][4][n] + S->aggT[2][4][n] + S->aggT[3][4][n];
      *(float4*)&S->aggC[n][0] = make_float4(a0, a1, a2, a3v);
      S->aggC[n][4] = dg;
    }
    __syncthreads();

    const int c = tid & 63, qq = tid >> 6;
    const float wc0 = S->w2s[c], wc1 = S->w2s[64 + c];
    const float wc2 = S->w2s[128 + c], wc3 = S->w2s[192 + c];
    const float b2c = S->b2s[c];
    float s = 0.f, ss = 0.f;
    for (int n = qq; n < 64; n += 4) {
      const float4 a = *(const float4*)&S->aggC[n][0];
      const float dg = S->aggC[n][4];
      float v = a.x * wc0 + a.y * wc1 + a.z * wc2 + a.w * wc3 + dg * b2c;
      ubuf0[(size_t)(((b << 6) + n) << 6) + c] = f2bf(v);
      s += v; ss += v * v;
    }
    S->rs[qq][c] = s; S->rss[qq][c] = ss;
    __syncthreads();
    if (tid < 64) {
      float* dst = stats1 + ((b & (REP - 1)) << 7);
      atomicAdd(&dst[tid], S->rs[0][tid] + S->rs[1][tid] + S->rs[2][tid] + S->rs[3][tid]);
      atomicAdd(&dst[64 + tid], S->rss[0][tid] + S->rss[1][tid] + S->rss[2][tid] + S->rss[3][tid]);
    }
  }

  gbar(bar + 0, GRID);
  conv_stage((SmemConv*)smem, b, tid, ubuf0, stats1, g1, be1, cwt2, c2b, ubuf1, stats2);
  gbar(bar + 16, GRID);
  conv_stage((SmemConv*)smem, b, tid, ubuf1, stats2, g2, be2, cwt3, c3b, ubuf0, stats3);
  gbar(bar + 32, GRID);

  // ======== S3: mlp1, grid (16 bx, 4 by, 16 bz), 4 chunks of 64 k ========
  {
    SmemMlp1* S = (SmemMlp1*)smem;
    const int bx = b & 15, by = (b >> 4) & 3, bz = b >> 6;
    if (tid < 64) {
      float sm = 0.f, sq = 0.f;
#pragma unroll 8
      for (int r = 0; r < REP; ++r) {
        sm += stats3[(r << 7) + tid];
        sq += stats3[(r << 7) + 64 + tid];
      }
      const float mean = sm * (1.0f / CNTF);
      const float var = sq * (1.0f / CNTF) - mean * mean;
      const float a = g3[tid] * rsqrtf(var + EPSV);
      S->a3s[tid] = a;
      S->b3s[tid] = be3[tid] - mean * a;
    }
    __syncthreads();

    const int lane = tid & 63, w = tid >> 6;
    const int lm = lane & 15, q = lane >> 4;
    const int gy = tid >> 2, py = (tid & 3) << 4;
    const int r8 = tid >> 2, c8 = (tid & 3) << 1;   // Ws staging map
    const int g0 = bx << 6, n0 = by << 6;

    f32x4 acc[4];
#pragma unroll
    for (int nt = 0; nt < 4; ++nt) acc[nt] = (f32x4){0.f, 0.f, 0.f, 0.f};
    const size_t ybase = ((size_t)(g0 + gy) << 12);

#pragma unroll 1
    for (int ck = 0; ck < 4; ++ck) {
      const int kcg = (bz << 2) + ck;
      const int kc = kcg << 6;
      if (ck) __syncthreads();
      {
        const ushort* src = ubuf0 + ybase + kc + py;
        const ushort8 r0 = *(const ushort8*)src;
        const ushort8 r1 = *(const ushort8*)(src + 8);
        ushort tmp[16];
#pragma unroll
        for (int j = 0; j < 8; ++j)
          tmp[j] = f2bf(fmaxf(fmaf(S->a3s[py + j], bf2f(r0[j]), S->b3s[py + j]), 0.f));
#pragma unroll
        for (int j = 0; j < 8; ++j)
          tmp[8 + j] = f2bf(fmaxf(fmaf(S->a3s[py + 8 + j], bf2f(r1[j]), S->b3s[py + 8 + j]), 0.f));
        *(ushort8*)&S->Ys[gy][py] = *(ushort8*)&tmp[0];
        *(ushort8*)&S->Ys[gy][py + 8] = *(ushort8*)&tmp[8];
      }
      {
        const ushort8* gw = (const ushort8*)(wbf1t + ((size_t)kcg << 14) + (n0 << 6));
        *(ushort8*)&S->Ws[r8][(c8 + 0) << 3] = gw[(r8 << 3) + c8 + 0];
        *(ushort8*)&S->Ws[r8][(c8 + 1) << 3] = gw[(r8 << 3) + c8 + 1];
      }
      __syncthreads();
#pragma unroll
      for (int ks = 0; ks < 2; ++ks) {
        const short8 af = *(const short8*)&S->Ys[(w << 4) + lm][(ks << 5) + (q << 3)];
#pragma unroll
        for (int nt = 0; nt < 4; ++nt) {
          const short8 bfr = *(const short8*)&S->Ws[(nt << 4) + lm][(ks << 5) + (q << 3)];
          acc[nt] = __builtin_amdgcn_mfma_f32_16x16x32_bf16(af, bfr, acc[nt], 0, 0, 0);
        }
      }
    }

    float* dst0 = h1part + ((size_t)bz << 18);
    const int gout = g0 + (w << 4) + (q << 2);
#pragma unroll
    for (int nt = 0; nt < 4; ++nt) {
      const int col = n0 + (nt << 4) + lm;
#pragma unroll
      for (int i = 0; i < 4; ++i)
        dst0[((size_t)(gout + i) << 8) + col] = acc[nt][i];
    }
  }
}

// ---------------------------------------------------------------------------
// k_tail: h1 = relu(sum_bz h1part + bm1) -> h2 -> h3 -> logits -> logsoftmax.
// 64 blocks x 16 graphs (proven R6 body; 16 partial slices).
// ---------------------------------------------------------------------------
__global__ __launch_bounds__(256) void k_tail(
    const float* __restrict__ h1part, const float* __restrict__ bm1,
    const ushort* __restrict__ wbf2t, const float* __restrict__ bm2,
    const ushort* __restrict__ wbf3t, const float* __restrict__ bm3,
    const ushort* __restrict__ wptbf, const float* __restrict__ bp,
    float* __restrict__ out)
{
  __shared__ ushort Ws[256][72];
  __shared__ ushort h1s[16][264];
  __shared__ ushort h2s[16][264];
  ushort* wpt = &Ws[0][0];
  const int tid = threadIdx.x;
  const int g0 = blockIdx.x << 4;
  const int lane = tid & 63, w = tid >> 6;
  const int lm = lane & 15, q = lane >> 4;
  const int gr = q << 2;

  {
    const int r = tid >> 4, c0 = (tid & 15) << 4;
    const float* srcb = h1part + ((size_t)(g0 + r) << 8) + c0;
#pragma unroll
    for (int i = 0; i < 4; ++i) {
      float4 vs = *(const float4*)(bm1 + c0 + (i << 2));
#pragma unroll 4
      for (int bz = 0; bz < 16; ++bz) {
        const float4 p = *(const float4*)(srcb + ((size_t)bz << 18) + (i << 2));
        vs.x += p.x; vs.y += p.y; vs.z += p.z; vs.w += p.w;
      }
      *(ushort4*)&h1s[r][c0 + (i << 2)] = make_ushort4(
          f2bf(fmaxf(vs.x, 0.f)), f2bf(fmaxf(vs.y, 0.f)),
          f2bf(fmaxf(vs.z, 0.f)), f2bf(fmaxf(vs.w, 0.f)));
    }
  }

  // ---- GEMM2
  f32x4 acc[4];
#pragma unroll
  for (int nt = 0; nt < 4; ++nt) acc[nt] = (f32x4){0.f, 0.f, 0.f, 0.f};
#pragma unroll 1
  for (int ck = 0; ck < 4; ++ck) {
    __syncthreads();
    {
      const ushort8* gw = (const ushort8*)(wbf2t + (ck << 14));
#pragma unroll
      for (int i = 0; i < 8; ++i) {
        const int e8 = (i << 8) + tid;
        *(ushort8*)&Ws[e8 >> 3][(e8 & 7) << 3] = gw[e8];
      }
    }
    __syncthreads();
#pragma unroll
    for (int ks = 0; ks < 2; ++ks) {
      const short8 af = *(const short8*)&h1s[lm][(ck << 6) + (ks << 5) + (q << 3)];
#pragma unroll
      for (int nt = 0; nt < 4; ++nt) {
        const short8 bfr = *(const short8*)&Ws[(w << 6) + (nt << 4) + lm][(ks << 5) + (q << 3)];
        acc[nt] = __builtin_amdgcn_mfma_f32_16x16x32_bf16(af, bfr, acc[nt], 0, 0, 0);
      }
    }
  }
#pragma unroll
  for (int nt = 0; nt < 4; ++nt) {
    const int col = (w << 6) + (nt << 4) + lm;
    const float bv = bm2[col];
#pragma unroll
    for (int i = 0; i < 4; ++i)
      h2s[gr + i][col] = f2bf(fmaxf(acc[nt][i] + bv, 0.f));
  }

  // ---- GEMM3
  f32x4 acc2[4];
#pragma unroll
  for (int nt = 0; nt < 4; ++nt) acc2[nt] = (f32x4){0.f, 0.f, 0.f, 0.f};
#pragma unroll 1
  for (int ck = 0; ck < 4; ++ck) {
    __syncthreads();
    {
      const ushort8* gw = (const ushort8*)(wbf3t + (ck << 14));
#pragma unroll
      for (int i = 0; i < 8; ++i) {
        const int e8 = (i << 8) + tid;
        *(ushort8*)&Ws[e8 >> 3][(e8 & 7) << 3] = gw[e8];
      }
    }
    __syncthreads();
#pragma unroll
    for (int ks = 0; ks < 2; ++ks) {
      const short8 af = *(const short8*)&h2s[lm][(ck << 6) + (ks << 5) + (q << 3)];
#pragma unroll
      for (int nt = 0; nt < 4; ++nt) {
        const short8 bfr = *(const short8*)&Ws[(w << 6) + (nt << 4) + lm][(ks << 5) + (q << 3)];
        acc2[nt] = __builtin_amdgcn_mfma_f32_16x16x32_bf16(af, bfr, acc2[nt], 0, 0, 0);
      }
    }
  }

  __syncthreads();
  {
    const ushort8* gw = (const ushort8*)wptbf;
#pragma unroll
    for (int i = 0; i < 2; ++i) {
      const int e8 = (i << 8) + tid;
      const int flat = e8 << 3;
      const int a = flat >> 8, kk = flat & 255;
      *(ushort8*)&wpt[a * 264 + kk] = gw[e8];
    }
  }
#pragma unroll
  for (int nt = 0; nt < 4; ++nt) {
    const int col = (w << 6) + (nt << 4) + lm;
    const float bv = bm3[col];
#pragma unroll
    for (int i = 0; i < 4; ++i)
      h2s[gr + i][col] = f2bf(fmaxf(acc2[nt][i] + bv, 0.f));
  }
  __syncthreads();

  if (w == 0) {
    f32x4 lacc = (f32x4){0.f, 0.f, 0.f, 0.f};
#pragma unroll
    for (int ks = 0; ks < 8; ++ks) {
      const short8 af = *(const short8*)&h2s[lm][(ks << 5) + (q << 3)];
      const short8 bfr = *(const short8*)&wpt[lm * 264 + (ks << 5) + (q << 3)];
      lacc = __builtin_amdgcn_mfma_f32_16x16x32_bf16(af, bfr, lacc, 0, 0, 0);
    }
    const float bpv = bp[lm];
    float lg[4], mx[4], se[4];
#pragma unroll
    for (int i = 0; i < 4; ++i) {
      lg[i] = lacc[i] + bpv;
      float m = lg[i];
#pragma unroll
      for (int off = 1; off < 16; off <<= 1) m = fmaxf(m, __shfl_xor(m, off));
      mx[i] = m;
      float e = expf(lg[i] - m);
#pragma unroll
      for (int off = 1; off < 16; off <<= 1) e += __shfl_xor(e, off);
      se[i] = e;
    }
#pragma unroll
    for (int i = 0; i < 4; ++i)
      out[((g0 + gr + i) << 4) + lm] = (lg[i] - mx[i]) - logf(se[i]);
  }
}

// ---------------------------------------------------------------------------
extern "C" void kernel_launch(void* const* d_in, const int* in_sizes, int n_in,
                              void* d_out, int out_size, void* d_ws, size_t ws_size,
                              hipStream_t stream)
{
  const float* x   = (const float*)d_in[0];
  const int*   ei  = (const int*)d_in[1];
  const float* w1  = (const float*)d_in[2];
  const float* b1  = (const float*)d_in[3];
  const float* w2  = (const float*)d_in[4];
  const float* b2  = (const float*)d_in[5];
  const float* c2w = (const float*)d_in[6];
  const float* c2b = (const float*)d_in[7];
  const float* c3w = (const float*)d_in[8];
  const float* c3b = (const float*)d_in[9];
  const float* g1  = (const float*)d_in[10];
  const float* be1 = (const float*)d_in[11];
  const float* g2  = (const float*)d_in[12];
  const float* be2 = (const float*)d_in[13];
  const float* g3  = (const float*)d_in[14];
  const float* be3 = (const float*)d_in[15];
  const float* wm1 = (const float*)d_in[16];
  const float* bm1 = (const float*)d_in[17];
  const float* wm2 = (const float*)d_in[18];
  const float* bm2 = (const float*)d_in[19];
  const float* wm3 = (const float*)d_in[20];
  const float* bm3 = (const float*)d_in[21];
  const float* wp  = (const float*)d_in[22];
  const float* bp  = (const float*)d_in[23];

  char* ws = (char*)d_ws;
  ushort* ubuf0 = (ushort*)ws;                          // 8 MiB bf16 out0->z3
  ushort* ubuf1 = (ushort*)(ws + ((size_t)8 << 20));    // 8 MiB bf16 z2
  float*  h1part = (float*)(ws + ((size_t)16 << 20));   // 16 MiB fp32 partials
  ushort* wbf1t = (ushort*)(ws + ((size_t)32 << 20));   // 2 MiB bf16 wm1^T
  ushort* wbf2t = (ushort*)(ws + ((size_t)34 << 20));               // 128 KiB
  ushort* wbf3t = (ushort*)(ws + ((size_t)34 << 20) + (128 << 10)); // 128 KiB
  ushort* wptbf = (ushort*)(ws + ((size_t)34 << 20) + (256 << 10)); // 8 KiB
  float* stats  = (float*)(ws + ((size_t)35 << 20));    // 48 KiB + barriers
  int*   bar    = (int*)(stats + 3 * REP * 128);        // 64 ints
  ushort* cwt2 = (ushort*)d_out;          // d_out scratch, overwritten by k_tail
  ushort* cwt3 = (ushort*)d_out + 12288;

  hipMemsetAsync(stats, 0, 3 * REP * 128 * sizeof(float) + 64 * sizeof(int),
                 stream);
  k_fused<<<dim3(GRID), dim3(256), 0, stream>>>(
      x, ei, w1, b1, w2, b2, c2w, c3w,
      g1, be1, c2b, g2, be2, c3b, g3, be3,
      wm1, wm2, wm3, wp,
      ubuf0, ubuf1, h1part, wbf1t, wbf2t, wbf3t, wptbf, stats,
      cwt2, cwt3, bar);
  k_tail<<<dim3(64), dim3(256), 0, stream>>>(h1part, bm1, wbf2t, bm2, wbf3t, bm3,
                                             wptbf, bp, (float*)d_out);
}

// Round 10
// 386.554 us; speedup vs baseline: 1.2600x; 1.2600x over previous
//
#include <hip/hip_runtime.h>
#include <cstdint>
#include <cstddef>

typedef __attribute__((ext_vector_type(8))) short short8;
typedef __attribute__((ext_vector_type(8))) unsigned short ushort8;
typedef __attribute__((ext_vector_type(4))) float f32x4;

#define EPSV 1e-5f
#define NEDGE 1048576
#define EPG 1024
#define CNTF 65536.0f
#define REP 32
#define GRID 1024
#define NLEAF 64
#define PERLEAF (GRID / NLEAF)
#define BARSTRIDE 2048   // ints per barrier slot

__device__ __forceinline__ ushort f2bf(float f) {
  uint u = __float_as_uint(f);
  return (ushort)((u + 0x7FFFu + ((u >> 16) & 1u)) >> 16);
}
__device__ __forceinline__ float bf2f(ushort u) {
  return __uint_as_float((uint)u << 16);
}

// Hierarchical grid barrier (counters zeroed by pre-launch memset).
// 64 cache-line-spaced leaf counters (16 RMWs each, parallel), root counter
// (64 RMWs), then a single released flag that everyone read-polls. Avoids the
// 1024-same-address RMW serialization that cost ~90us/barrier in R8.
// All GRID blocks co-resident: LDS 36,384B & __launch_bounds__(256,4).
__device__ __forceinline__ void gbar(int* base) {
  __syncthreads();
  if (threadIdx.x == 0) {
    __threadfence();                                   // release
    const int li = blockIdx.x & (NLEAF - 1);
    const int prev = __hip_atomic_fetch_add(base + li * 16, 1,
        __ATOMIC_ACQ_REL, __HIP_MEMORY_SCOPE_AGENT);
    if (prev == PERLEAF - 1) {
      const int r = __hip_atomic_fetch_add(base + 1024, 1,
          __ATOMIC_ACQ_REL, __HIP_MEMORY_SCOPE_AGENT);
      if (r == NLEAF - 1)
        __hip_atomic_store(base + 1040, 1, __ATOMIC_RELEASE,
                           __HIP_MEMORY_SCOPE_AGENT);
    }
    while (__hip_atomic_load(base + 1040, __ATOMIC_RELAXED,
                             __HIP_MEMORY_SCOPE_AGENT) == 0)
      __builtin_amdgcn_s_sleep(16);
    __threadfence();                                   // acquire
  }
  __syncthreads();
}

// ---- shared-memory union (max = SmemConv = 36384 B -> 4 blocks/CU)
struct SmemEdge {
  float xs[64];
  float aggT[4][5][72];
  float aggC[64][8];
  float w1s[8], b1s[4];
  float w2s[256], b2s[64];
  float rs[4][64], rss[4][64];
};
struct SmemPrep { ushort T[64][72]; };
struct SmemConv {
  ushort As[64][200];
  ushort Yt[66][72];
  float aco[64], bco[64], cbs[64];
  float ldsS[64], ldsSS[64];
};
struct SmemMlp1 {
  float a3s[64], b3s[64];
  ushort Ys[64][72];
  ushort Ws[64][72];
};

// ---------------------------------------------------------------------------
// conv stage, one graph per block (proven shape).
// ---------------------------------------------------------------------------
__device__ __forceinline__ void conv_stage(
    SmemConv* S, const int g, const int tid,
    const ushort* __restrict__ in, const float* __restrict__ stats_in,
    const float* __restrict__ gamma, const float* __restrict__ beta,
    const ushort* __restrict__ cwt, const float* __restrict__ cb,
    ushort* __restrict__ out, float* __restrict__ stats_out)
{
  if (tid < 64) {
    float sm = 0.f, sq = 0.f;
#pragma unroll 8
    for (int r = 0; r < REP; ++r) {
      sm += stats_in[(r << 7) + tid];
      sq += stats_in[(r << 7) + 64 + tid];
    }
    const float mean = sm * (1.0f / CNTF);
    const float var = sq * (1.0f / CNTF) - mean * mean;
    const float a = gamma[tid] * rsqrtf(var + EPSV);
    S->aco[tid] = a;
    S->bco[tid] = beta[tid] - mean * a;
    S->cbs[tid] = cb[tid];
    S->Yt[0][tid] = 0;
    S->Yt[65][tid] = 0;
  }
  {
    const ushort8* gw = (const ushort8*)cwt;
#pragma unroll
    for (int i = 0; i < 6; ++i) {
      const int e8 = (i << 8) + tid;
      const int o = e8 / 24, k8 = (e8 - o * 24) << 3;
      *(ushort8*)&S->As[o][k8] = gw[e8];
    }
  }
  __syncthreads();

  const size_t base = (size_t)g << 12;
  {
    const int lr = tid >> 2, p = (tid & 3) << 4;
    const ushort8 r0 = *(const ushort8*)&in[base + (lr << 6) + p];
    const ushort8 r1 = *(const ushort8*)&in[base + (lr << 6) + p + 8];
    ushort tmp[16];
#pragma unroll
    for (int j = 0; j < 8; ++j)
      tmp[j] = f2bf(fmaxf(fmaf(S->aco[p + j], bf2f(r0[j]), S->bco[p + j]), 0.f));
#pragma unroll
    for (int j = 0; j < 8; ++j)
      tmp[8 + j] = f2bf(fmaxf(fmaf(S->aco[p + 8 + j], bf2f(r1[j]), S->bco[p + 8 + j]), 0.f));
    *(ushort8*)&S->Yt[lr + 1][p] = *(ushort8*)&tmp[0];
    *(ushort8*)&S->Yt[lr + 1][p + 8] = *(ushort8*)&tmp[8];
  }
  __syncthreads();

  const int lane = tid & 63, w = tid >> 6;
  const int lm = lane & 15, q = lane >> 4;
  f32x4 acc[4];
#pragma unroll
  for (int nt = 0; nt < 4; ++nt) acc[nt] = (f32x4){0.f, 0.f, 0.f, 0.f};
#pragma unroll
  for (int kk = 0; kk < 3; ++kk) {
#pragma unroll
    for (int ks = 0; ks < 2; ++ks) {
      const short8 af = *(const short8*)&S->As[(w << 4) + lm][(kk << 6) + (ks << 5) + (q << 3)];
#pragma unroll
      for (int nt = 0; nt < 4; ++nt) {
        const short8 bfr = *(const short8*)&S->Yt[(nt << 4) + lm + kk][(ks << 5) + (q << 3)];
        acc[nt] = __builtin_amdgcn_mfma_f32_16x16x32_bf16(af, bfr, acc[nt], 0, 0, 0);
      }
    }
  }

  const int obase = (w << 4) + (q << 2);
  const float4 cb4 = *(const float4*)&S->cbs[obase];
  float s[4] = {0.f, 0.f, 0.f, 0.f}, ss[4] = {0.f, 0.f, 0.f, 0.f};
#pragma unroll
  for (int nt = 0; nt < 4; ++nt) {
    const int l = (nt << 4) + lm;
    float4 v = make_float4(acc[nt][0] + cb4.x, acc[nt][1] + cb4.y,
                           acc[nt][2] + cb4.z, acc[nt][3] + cb4.w);
    *(ushort4*)&out[base + (l << 6) + obase] =
        make_ushort4(f2bf(v.x), f2bf(v.y), f2bf(v.z), f2bf(v.w));
    s[0] += v.x; ss[0] += v.x * v.x;
    s[1] += v.y; ss[1] += v.y * v.y;
    s[2] += v.z; ss[2] += v.z * v.z;
    s[3] += v.w; ss[3] += v.w * v.w;
  }
#pragma unroll
  for (int i = 0; i < 4; ++i) {
#pragma unroll
    for (int off = 1; off < 16; off <<= 1) {
      s[i] += __shfl_xor(s[i], off);
      ss[i] += __shfl_xor(ss[i], off);
    }
    if (lm == 0) { S->ldsS[obase + i] = s[i]; S->ldsSS[obase + i] = ss[i]; }
  }
  __syncthreads();
  if (tid < 64) {
    float* dst = stats_out + ((g & (REP - 1)) << 7);
    atomicAdd(&dst[tid], S->ldsS[tid]);
    atomicAdd(&dst[64 + tid], S->ldsSS[tid]);
  }
}

// ---------------------------------------------------------------------------
// k_fused: prep+edge | conv2 | conv3 | mlp1, 1024 blocks, hierarchical
// grid barriers.
// ---------------------------------------------------------------------------
__global__ __launch_bounds__(256, 4) void k_fused(
    const float* __restrict__ x, const int* __restrict__ ei,
    const float* __restrict__ w1, const float* __restrict__ b1,
    const float* __restrict__ w2, const float* __restrict__ b2,
    const float* __restrict__ c2w, const float* __restrict__ c3w,
    const float* __restrict__ g1, const float* __restrict__ be1,
    const float* __restrict__ c2b,
    const float* __restrict__ g2, const float* __restrict__ be2,
    const float* __restrict__ c3b,
    const float* __restrict__ g3, const float* __restrict__ be3,
    const float* __restrict__ wm1, const float* __restrict__ wm2,
    const float* __restrict__ wm3, const float* __restrict__ wp,
    ushort* __restrict__ ubuf0, ushort* __restrict__ ubuf1,
    float* __restrict__ h1part, ushort* __restrict__ wbf1t,
    ushort* __restrict__ wbf2t, ushort* __restrict__ wbf3t,
    ushort* __restrict__ wptbf, float* __restrict__ stats,
    ushort* __restrict__ cwt2, ushort* __restrict__ cwt3,
    int* __restrict__ bar)
{
  __shared__ __align__(16) char smem[sizeof(SmemConv)];
  const int tid = threadIdx.x;
  const int b = blockIdx.x;
  float* stats1 = stats;
  float* stats2 = stats + REP * 128;
  float* stats3 = stats + 2 * REP * 128;

  // ======== S0a: weight prep (disjoint block ranges) ========
  if (b < 256) {           // wm1 -> wbf1t chunk-major (row-perm k' = l*64+c)
    SmemPrep* P = (SmemPrep*)smem;
    const int kc = b >> 2, n0 = (b & 3) << 6;
    const int kk = tid >> 2, np = (tid & 3) << 4;
    const float* srow = wm1 + (((size_t)(kk << 6) + kc) << 8) + n0 + np;
#pragma unroll
    for (int i = 0; i < 4; ++i) {
      const float4 v = *(const float4*)(srow + (i << 2));
      const int n = np + (i << 2);
      P->T[n + 0][kk] = f2bf(v.x); P->T[n + 1][kk] = f2bf(v.y);
      P->T[n + 2][kk] = f2bf(v.z); P->T[n + 3][kk] = f2bf(v.w);
    }
    __syncthreads();
    ushort* dst = wbf1t + ((size_t)kc << 14) + (n0 << 6);
    const int nl = tid >> 2, qk = (tid & 3) << 4;
    *(ushort8*)(dst + (nl << 6) + qk) = *(ushort8*)&P->T[nl][qk];
    *(ushort8*)(dst + (nl << 6) + qk + 8) = *(ushort8*)&P->T[nl][qk + 8];
    __syncthreads();       // done with P->T before edge reuses LDS
  } else if (b < 320) {    // wm2/wm3 -> chunk-major
    const int base = (((b - 256) << 8) + tid) << 3;
    const int m = base >> 16;
    const int rem = base & 65535;
    const int kc = rem >> 14, within = rem & 16383;
    const int n = within >> 6, kk0 = within & 63;
    const float* src = m ? wm3 : wm2;
    ushort* dst = m ? wbf3t : wbf2t;
    ushort tmp[8];
#pragma unroll
    for (int j = 0; j < 8; ++j)
      tmp[j] = f2bf(src[(((kc << 6) | (kk0 + j)) << 8) + n]);
    *(ushort8*)&dst[rem] = *(ushort8*)&tmp[0];
  } else if (b == 320) {   // wp -> wp^T
    const int a = tid & 15, k0 = (tid >> 4) << 4;
    ushort tmp[16];
#pragma unroll
    for (int j = 0; j < 16; ++j) tmp[j] = f2bf(wp[((k0 + j) << 4) + a]);
    *(ushort8*)&wptbf[(a << 8) + k0] = *(ushort8*)&tmp[0];
    *(ushort8*)&wptbf[(a << 8) + k0 + 8] = *(ushort8*)&tmp[8];
  } else if (b < 417) {    // conv weights -> cwt (d_out scratch)
    const int flat = (b - 321) * 256 + tid;
    const int m = flat >= 12288;
    const int idx = flat - (m ? 12288 : 0);
    const float* src = m ? c3w : c2w;
    ushort* dst = m ? cwt3 : cwt2;
    const int o = idx / 192, rem2 = idx - o * 192;
    const int kk = rem2 >> 6, c = rem2 & 63;
    dst[idx] = f2bf(src[o * 192 + c * 3 + kk]);
  }

  // ======== S0b: EdgeConv, graph b (proven shape) ========
  {
    SmemEdge* S = (SmemEdge*)smem;
    const int w = tid >> 6;
    if (tid < 8) S->w1s[tid] = w1[tid];
    if (tid < 4) S->b1s[tid] = b1[tid];
    if (tid < 64) { S->xs[tid] = x[(b << 6) + tid]; S->b2s[tid] = b2[tid]; }
    S->w2s[tid] = w2[tid];
    for (int i = tid; i < 1440; i += 256) ((float*)S->aggT)[i] = 0.f;
    __syncthreads();

    const int e0 = b * EPG;
    const int4 s4 = ((const int4*)(ei + e0))[tid];
    const int4 d4 = ((const int4*)(ei + NEDGE + e0))[tid];
    float* agw = &S->aggT[w][0][0];
    const int sls[4] = {s4.x & 63, s4.y & 63, s4.z & 63, s4.w & 63};
    const int dls[4] = {d4.x & 63, d4.y & 63, d4.z & 63, d4.w & 63};
#pragma unroll
    for (int e = 0; e < 4; ++e) {
      const int dl = dls[e];
      const float xi = S->xs[dl];
      const float dx = S->xs[sls[e]] - xi;
#pragma unroll
      for (int j = 0; j < 4; ++j) {
        float h = fmaxf(fmaf(xi, S->w1s[j], fmaf(dx, S->w1s[4 + j], S->b1s[j])), 0.f);
        atomicAdd(&agw[j * 72 + dl], h);
      }
      atomicAdd(&agw[4 * 72 + dl], 1.0f);
    }
    __syncthreads();

    if (tid < 64) {
      const int n = tid;
      const float a0 = S->aggT[0][0][n] + S->aggT[1][0][n] + S->aggT[2][0][n] + S->aggT[3][0][n];
      const float a1 = S->aggT[0][1][n] + S->aggT[1][1][n] + S->aggT[2][1][n] + S->aggT[3][1][n];
      const float a2 = S->aggT[0][2][n] + S->aggT[1][2][n] + S->aggT[2][2][n] + S->aggT[3][2][n];
      const float a3v = S->aggT[0][3][n] + S->aggT[1][3][n] + S->aggT[2][3][n] + S->aggT[3][3][n];
      const float dg = S->aggT[0][4][n] + S->aggT[1][4][n] + S->aggT[2][4][n] + S->aggT[3][4][n];
      *(float4*)&S->aggC[n][0] = make_float4(a0, a1, a2, a3v);
      S->aggC[n][4] = dg;
    }
    __syncthreads();

    const int c = tid & 63, qq = tid >> 6;
    const float wc0 = S->w2s[c], wc1 = S->w2s[64 + c];
    const float wc2 = S->w2s[128 + c], wc3 = S->w2s[192 + c];
    const float b2c = S->b2s[c];
    float s = 0.f, ss = 0.f;
    for (int n = qq; n < 64; n += 4) {
      const float4 a = *(const float4*)&S->aggC[n][0];
      const float dg = S->aggC[n][4];
      float v = a.x * wc0 + a.y * wc1 + a.z * wc2 + a.w * wc3 + dg * b2c;
      ubuf0[(size_t)(((b << 6) + n) << 6) + c] = f2bf(v);
      s += v; ss += v * v;
    }
    S->rs[qq][c] = s; S->rss[qq][c] = ss;
    __syncthreads();
    if (tid < 64) {
      float* dst = stats1 + ((b & (REP - 1)) << 7);
      atomicAdd(&dst[tid], S->rs[0][tid] + S->rs[1][tid] + S->rs[2][tid] + S->rs[3][tid]);
      atomicAdd(&dst[64 + tid], S->rss[0][tid] + S->rss[1][tid] + S->rss[2][tid] + S->rss[3][tid]);
    }
  }

  gbar(bar + 0 * BARSTRIDE);
  conv_stage((SmemConv*)smem, b, tid, ubuf0, stats1, g1, be1, cwt2, c2b, ubuf1, stats2);
  gbar(bar + 1 * BARSTRIDE);
  conv_stage((SmemConv*)smem, b, tid, ubuf1, stats2, g2, be2, cwt3, c3b, ubuf0, stats3);
  gbar(bar + 2 * BARSTRIDE);

  // ======== S3: mlp1, grid (16 bx, 4 by, 16 bz), 4 chunks of 64 k ========
  {
    SmemMlp1* S = (SmemMlp1*)smem;
    const int bx = b & 15, by = (b >> 4) & 3, bz = b >> 6;
    if (tid < 64) {
      float sm = 0.f, sq = 0.f;
#pragma unroll 8
      for (int r = 0; r < REP; ++r) {
        sm += stats3[(r << 7) + tid];
        sq += stats3[(r << 7) + 64 + tid];
      }
      const float mean = sm * (1.0f / CNTF);
      const float var = sq * (1.0f / CNTF) - mean * mean;
      const float a = g3[tid] * rsqrtf(var + EPSV);
      S->a3s[tid] = a;
      S->b3s[tid] = be3[tid] - mean * a;
    }
    __syncthreads();

    const int lane = tid & 63, w = tid >> 6;
    const int lm = lane & 15, q = lane >> 4;
    const int gy = tid >> 2, py = (tid & 3) << 4;
    const int r8 = tid >> 2, c8 = (tid & 3) << 1;   // Ws staging map
    const int g0 = bx << 6, n0 = by << 6;

    f32x4 acc[4];
#pragma unroll
    for (int nt = 0; nt < 4; ++nt) acc[nt] = (f32x4){0.f, 0.f, 0.f, 0.f};
    const size_t ybase = ((size_t)(g0 + gy) << 12);

#pragma unroll 1
    for (int ck = 0; ck < 4; ++ck) {
      const int kcg = (bz << 2) + ck;
      const int kc = kcg << 6;
      if (ck) __syncthreads();
      {
        const ushort* src = ubuf0 + ybase + kc + py;
        const ushort8 r0 = *(const ushort8*)src;
        const ushort8 r1 = *(const ushort8*)(src + 8);
        ushort tmp[16];
#pragma unroll
        for (int j = 0; j < 8; ++j)
          tmp[j] = f2bf(fmaxf(fmaf(S->a3s[py + j], bf2f(r0[j]), S->b3s[py + j]), 0.f));
#pragma unroll
        for (int j = 0; j < 8; ++j)
          tmp[8 + j] = f2bf(fmaxf(fmaf(S->a3s[py + 8 + j], bf2f(r1[j]), S->b3s[py + 8 + j]), 0.f));
        *(ushort8*)&S->Ys[gy][py] = *(ushort8*)&tmp[0];
        *(ushort8*)&S->Ys[gy][py + 8] = *(ushort8*)&tmp[8];
      }
      {
        const ushort8* gw = (const ushort8*)(wbf1t + ((size_t)kcg << 14) + (n0 << 6));
        *(ushort8*)&S->Ws[r8][(c8 + 0) << 3] = gw[(r8 << 3) + c8 + 0];
        *(ushort8*)&S->Ws[r8][(c8 + 1) << 3] = gw[(r8 << 3) + c8 + 1];
      }
      __syncthreads();
#pragma unroll
      for (int ks = 0; ks < 2; ++ks) {
        const short8 af = *(const short8*)&S->Ys[(w << 4) + lm][(ks << 5) + (q << 3)];
#pragma unroll
        for (int nt = 0; nt < 4; ++nt) {
          const short8 bfr = *(const short8*)&S->Ws[(nt << 4) + lm][(ks << 5) + (q << 3)];
          acc[nt] = __builtin_amdgcn_mfma_f32_16x16x32_bf16(af, bfr, acc[nt], 0, 0, 0);
        }
      }
    }

    float* dst0 = h1part + ((size_t)bz << 18);
    const int gout = g0 + (w << 4) + (q << 2);
#pragma unroll
    for (int nt = 0; nt < 4; ++nt) {
      const int col = n0 + (nt << 4) + lm;
#pragma unroll
      for (int i = 0; i < 4; ++i)
        dst0[((size_t)(gout + i) << 8) + col] = acc[nt][i];
    }
  }
}

// ---------------------------------------------------------------------------
// k_tail: h1 = relu(sum_bz h1part + bm1) -> h2 -> h3 -> logits -> logsoftmax.
// 64 blocks x 16 graphs (proven body; 16 partial slices).
// ---------------------------------------------------------------------------
__global__ __launch_bounds__(256) void k_tail(
    const float* __restrict__ h1part, const float* __restrict__ bm1,
    const ushort* __restrict__ wbf2t, const float* __restrict__ bm2,
    const ushort* __restrict__ wbf3t, const float* __restrict__ bm3,
    const ushort* __restrict__ wptbf, const float* __restrict__ bp,
    float* __restrict__ out)
{
  __shared__ ushort Ws[256][72];
  __shared__ ushort h1s[16][264];
  __shared__ ushort h2s[16][264];
  ushort* wpt = &Ws[0][0];
  const int tid = threadIdx.x;
  const int g0 = blockIdx.x << 4;
  const int lane = tid & 63, w = tid >> 6;
  const int lm = lane & 15, q = lane >> 4;
  const int gr = q << 2;

  {
    const int r = tid >> 4, c0 = (tid & 15) << 4;
    const float* srcb = h1part + ((size_t)(g0 + r) << 8) + c0;
#pragma unroll
    for (int i = 0; i < 4; ++i) {
      float4 vs = *(const float4*)(bm1 + c0 + (i << 2));
#pragma unroll 4
      for (int bz = 0; bz < 16; ++bz) {
        const float4 p = *(const float4*)(srcb + ((size_t)bz << 18) + (i << 2));
        vs.x += p.x; vs.y += p.y; vs.z += p.z; vs.w += p.w;
      }
      *(ushort4*)&h1s[r][c0 + (i << 2)] = make_ushort4(
          f2bf(fmaxf(vs.x, 0.f)), f2bf(fmaxf(vs.y, 0.f)),
          f2bf(fmaxf(vs.z, 0.f)), f2bf(fmaxf(vs.w, 0.f)));
    }
  }

  // ---- GEMM2
  f32x4 acc[4];
#pragma unroll
  for (int nt = 0; nt < 4; ++nt) acc[nt] = (f32x4){0.f, 0.f, 0.f, 0.f};
#pragma unroll 1
  for (int ck = 0; ck < 4; ++ck) {
    __syncthreads();
    {
      const ushort8* gw = (const ushort8*)(wbf2t + (ck << 14));
#pragma unroll
      for (int i = 0; i < 8; ++i) {
        const int e8 = (i << 8) + tid;
        *(ushort8*)&Ws[e8 >> 3][(e8 & 7) << 3] = gw[e8];
      }
    }
    __syncthreads();
#pragma unroll
    for (int ks = 0; ks < 2; ++ks) {
      const short8 af = *(const short8*)&h1s[lm][(ck << 6) + (ks << 5) + (q << 3)];
#pragma unroll
      for (int nt = 0; nt < 4; ++nt) {
        const short8 bfr = *(const short8*)&Ws[(w << 6) + (nt << 4) + lm][(ks << 5) + (q << 3)];
        acc[nt] = __builtin_amdgcn_mfma_f32_16x16x32_bf16(af, bfr, acc[nt], 0, 0, 0);
      }
    }
  }
#pragma unroll
  for (int nt = 0; nt < 4; ++nt) {
    const int col = (w << 6) + (nt << 4) + lm;
    const float bv = bm2[col];
#pragma unroll
    for (int i = 0; i < 4; ++i)
      h2s[gr + i][col] = f2bf(fmaxf(acc[nt][i] + bv, 0.f));
  }

  // ---- GEMM3
  f32x4 acc2[4];
#pragma unroll
  for (int nt = 0; nt < 4; ++nt) acc2[nt] = (f32x4){0.f, 0.f, 0.f, 0.f};
#pragma unroll 1
  for (int ck = 0; ck < 4; ++ck) {
    __syncthreads();
    {
      const ushort8* gw = (const ushort8*)(wbf3t + (ck << 14));
#pragma unroll
      for (int i = 0; i < 8; ++i) {
        const int e8 = (i << 8) + tid;
        *(ushort8*)&Ws[e8 >> 3][(e8 & 7) << 3] = gw[e8];
      }
    }
    __syncthreads();
#pragma unroll
    for (int ks = 0; ks < 2; ++ks) {
      const short8 af = *(const short8*)&h2s[lm][(ck << 6) + (ks << 5) + (q << 3)];
#pragma unroll
      for (int nt = 0; nt < 4; ++nt) {
        const short8 bfr = *(const short8*)&Ws[(w << 6) + (nt << 4) + lm][(ks << 5) + (q << 3)];
        acc2[nt] = __builtin_amdgcn_mfma_f32_16x16x32_bf16(af, bfr, acc2[nt], 0, 0, 0);
      }
    }
  }

  __syncthreads();
  {
    const ushort8* gw = (const ushort8*)wptbf;
#pragma unroll
    for (int i = 0; i < 2; ++i) {
      const int e8 = (i << 8) + tid;
      const int flat = e8 << 3;
      const int a = flat >> 8, kk = flat & 255;
      *(ushort8*)&wpt[a * 264 + kk] = gw[e8];
    }
  }
#pragma unroll
  for (int nt = 0; nt < 4; ++nt) {
    const int col = (w << 6) + (nt << 4) + lm;
    const float bv = bm3[col];
#pragma unroll
    for (int i = 0; i < 4; ++i)
      h2s[gr + i][col] = f2bf(fmaxf(acc2[nt][i] + bv, 0.f));
  }
  __syncthreads();

  if (w == 0) {
    f32x4 lacc = (f32x4){0.f, 0.f, 0.f, 0.f};
#pragma unroll
    for (int ks = 0; ks < 8; ++ks) {
      const short8 af = *(const short8*)&h2s[lm][(ks << 5) + (q << 3)];
      const short8 bfr = *(const short8*)&wpt[lm * 264 + (ks << 5) + (q << 3)];
      lacc = __builtin_amdgcn_mfma_f32_16x16x32_bf16(af, bfr, lacc, 0, 0, 0);
    }
    const float bpv = bp[lm];
    float lg[4], mx[4], se[4];
#pragma unroll
    for (int i = 0; i < 4; ++i) {
      lg[i] = lacc[i] + bpv;
      float m = lg[i];
#pragma unroll
      for (int off = 1; off < 16; off <<= 1) m = fmaxf(m, __shfl_xor(m, off));
      mx[i] = m;
      float e = expf(lg[i] - m);
#pragma unroll
      for (int off = 1; off < 16; off <<= 1) e += __shfl_xor(e, off);
      se[i] = e;
    }
#pragma unroll
    for (int i = 0; i < 4; ++i)
      out[((g0 + gr + i) << 4) + lm] = (lg[i] - mx[i]) - logf(se[i]);
  }
}

// ---------------------------------------------------------------------------
extern "C" void kernel_launch(void* const* d_in, const int* in_sizes, int n_in,
                              void* d_out, int out_size, void* d_ws, size_t ws_size,
                              hipStream_t stream)
{
  const float* x   = (const float*)d_in[0];
  const int*   ei  = (const int*)d_in[1];
  const float* w1  = (const float*)d_in[2];
  const float* b1  = (const float*)d_in[3];
  const float* w2  = (const float*)d_in[4];
  const float* b2  = (const float*)d_in[5];
  const float* c2w = (const float*)d_in[6];
  const float* c2b = (const float*)d_in[7];
  const float* c3w = (const float*)d_in[8];
  const float* c3b = (const float*)d_in[9];
  const float* g1  = (const float*)d_in[10];
  const float* be1 = (const float*)d_in[11];
  const float* g2  = (const float*)d_in[12];
  const float* be2 = (const float*)d_in[13];
  const float* g3  = (const float*)d_in[14];
  const float* be3 = (const float*)d_in[15];
  const float* wm1 = (const float*)d_in[16];
  const float* bm1 = (const float*)d_in[17];
  const float* wm2 = (const float*)d_in[18];
  const float* bm2 = (const float*)d_in[19];
  const float* wm3 = (const float*)d_in[20];
  const float* bm3 = (const float*)d_in[21];
  const float* wp  = (const float*)d_in[22];
  const float* bp  = (const float*)d_in[23];

  char* ws = (char*)d_ws;
  ushort* ubuf0 = (ushort*)ws;                          // 8 MiB bf16 out0->z3
  ushort* ubuf1 = (ushort*)(ws + ((size_t)8 << 20));    // 8 MiB bf16 z2
  float*  h1part = (float*)(ws + ((size_t)16 << 20));   // 16 MiB fp32 partials
  ushort* wbf1t = (ushort*)(ws + ((size_t)32 << 20));   // 2 MiB bf16 wm1^T
  ushort* wbf2t = (ushort*)(ws + ((size_t)34 << 20));               // 128 KiB
  ushort* wbf3t = (ushort*)(ws + ((size_t)34 << 20) + (128 << 10)); // 128 KiB
  ushort* wptbf = (ushort*)(ws + ((size_t)34 << 20) + (256 << 10)); // 8 KiB
  float* stats  = (float*)(ws + ((size_t)35 << 20));    // 48 KiB
  int*   bar    = (int*)(stats + 3 * REP * 128);        // 4 barriers x 8 KiB
  ushort* cwt2 = (ushort*)d_out;          // d_out scratch, overwritten by k_tail
  ushort* cwt3 = (ushort*)d_out + 12288;

  hipMemsetAsync(stats, 0,
                 3 * REP * 128 * sizeof(float) + 4 * BARSTRIDE * sizeof(int),
                 stream);
  k_fused<<<dim3(GRID), dim3(256), 0, stream>>>(
      x, ei, w1, b1, w2, b2, c2w, c3w,
      g1, be1, c2b, g2, be2, c3b, g3, be3,
      wm1, wm2, wm3, wp,
      ubuf0, ubuf1, h1part, wbf1t, wbf2t, wbf3t, wptbf, stats,
      cwt2, cwt3, bar);
  k_tail<<<dim3(64), dim3(256), 0, stream>>>(h1part, bm1, wbf2t, bm2, wbf3t, bm3,
                                             wptbf, bp, (float*)d_out);
}

// Round 11
// 254.494 us; speedup vs baseline: 1.9138x; 1.5189x over previous
//
#include <hip/hip_runtime.h>
#include <cstdint>
#include <cstddef>

typedef __attribute__((ext_vector_type(8))) short short8;
typedef __attribute__((ext_vector_type(8))) unsigned short ushort8;
typedef __attribute__((ext_vector_type(4))) float f32x4;

#define EPSV 1e-5f
#define NEDGE 1048576
#define EPG 1024
#define CNTF 65536.0f
#define REP 32

__device__ __forceinline__ ushort f2bf(float f) {
  uint u = __float_as_uint(f);
  return (ushort)((u + 0x7FFFu + ((u >> 16) & 1u)) >> 16);
}
__device__ __forceinline__ float bf2f(ushort u) {
  return __uint_as_float((uint)u << 16);
}

// ---- per-kernel shared-memory unions
struct SmemEdge {
  float xs[64];
  float aggT[4][5][72];
  float aggC[64][8];
  float w1s[8], b1s[4];
  float w2s[256], b2s[64];
  float rs[4][64], rss[4][64];
};
struct SmemPrep { ushort T[64][72]; };
struct SmemMlp1 {                    // 18944 B
  float a3s[64], b3s[64];
  ushort Ys[64][72];
  ushort Ws[64][72];
};
struct SmemTailH {                   // 35328 B (half-staged tail, R7-proven)
  ushort Ws[128][72];                // wpt [16][264] view reuses this
  ushort h1s[16][264];
  ushort h2s[16][264];
};

// ---------------------------------------------------------------------------
// k_edgeprep: weight prep side-work (disjoint block ranges) + EdgeConv for
// graph b. 1024 blocks. (R9 S0 body, proven.)
// ---------------------------------------------------------------------------
__global__ __launch_bounds__(256, 4) void k_edgeprep(
    const float* __restrict__ x, const int* __restrict__ ei,
    const float* __restrict__ w1, const float* __restrict__ b1,
    const float* __restrict__ w2, const float* __restrict__ b2,
    const float* __restrict__ c2w, const float* __restrict__ c3w,
    const float* __restrict__ wm1, const float* __restrict__ wm2,
    const float* __restrict__ wm3, const float* __restrict__ wp,
    ushort* __restrict__ ubuf0, ushort* __restrict__ wbf1t,
    ushort* __restrict__ wbf2t, ushort* __restrict__ wbf3t,
    ushort* __restrict__ wptbf, float* __restrict__ stats1,
    ushort* __restrict__ cwt2, ushort* __restrict__ cwt3)
{
  __shared__ __align__(16) char smem[sizeof(SmemEdge)];
  const int tid = threadIdx.x;
  const int b = blockIdx.x;

  // ---- prep side-work
  if (b < 256) {           // wm1 -> wbf1t chunk-major (row-perm k' = l*64+c)
    SmemPrep* P = (SmemPrep*)smem;
    const int kc = b >> 2, n0 = (b & 3) << 6;
    const int kk = tid >> 2, np = (tid & 3) << 4;
    const float* srow = wm1 + (((size_t)(kk << 6) + kc) << 8) + n0 + np;
#pragma unroll
    for (int i = 0; i < 4; ++i) {
      const float4 v = *(const float4*)(srow + (i << 2));
      const int n = np + (i << 2);
      P->T[n + 0][kk] = f2bf(v.x); P->T[n + 1][kk] = f2bf(v.y);
      P->T[n + 2][kk] = f2bf(v.z); P->T[n + 3][kk] = f2bf(v.w);
    }
    __syncthreads();
    ushort* dst = wbf1t + ((size_t)kc << 14) + (n0 << 6);
    const int nl = tid >> 2, qk = (tid & 3) << 4;
    *(ushort8*)(dst + (nl << 6) + qk) = *(ushort8*)&P->T[nl][qk];
    *(ushort8*)(dst + (nl << 6) + qk + 8) = *(ushort8*)&P->T[nl][qk + 8];
    __syncthreads();       // finish T reads before edge reuses LDS
  } else if (b < 320) {    // wm2/wm3 -> chunk-major [kc][n][kk]
    const int base = (((b - 256) << 8) + tid) << 3;
    const int m = base >> 16;
    const int rem = base & 65535;
    const int kc = rem >> 14, within = rem & 16383;
    const int n = within >> 6, kk0 = within & 63;
    const float* src = m ? wm3 : wm2;
    ushort* dst = m ? wbf3t : wbf2t;
    ushort tmp[8];
#pragma unroll
    for (int j = 0; j < 8; ++j)
      tmp[j] = f2bf(src[(((kc << 6) | (kk0 + j)) << 8) + n]);
    *(ushort8*)&dst[rem] = *(ushort8*)&tmp[0];
  } else if (b == 320) {   // wp -> wp^T
    const int a = tid & 15, k0 = (tid >> 4) << 4;
    ushort tmp[16];
#pragma unroll
    for (int j = 0; j < 16; ++j) tmp[j] = f2bf(wp[((k0 + j) << 4) + a]);
    *(ushort8*)&wptbf[(a << 8) + k0] = *(ushort8*)&tmp[0];
    *(ushort8*)&wptbf[(a << 8) + k0 + 8] = *(ushort8*)&tmp[8];
  } else if (b < 417) {    // conv weights -> cwt (d_out scratch)
    const int flat = (b - 321) * 256 + tid;
    const int m = flat >= 12288;
    const int idx = flat - (m ? 12288 : 0);
    const float* src = m ? c3w : c2w;
    ushort* dst = m ? cwt3 : cwt2;
    const int o = idx / 192, rem2 = idx - o * 192;
    const int kk = rem2 >> 6, c = rem2 & 63;
    dst[idx] = f2bf(src[o * 192 + c * 3 + kk]);
  }

  // ---- EdgeConv, graph b
  {
    SmemEdge* S = (SmemEdge*)smem;
    const int w = tid >> 6;
    if (tid < 8) S->w1s[tid] = w1[tid];
    if (tid < 4) S->b1s[tid] = b1[tid];
    if (tid < 64) { S->xs[tid] = x[(b << 6) + tid]; S->b2s[tid] = b2[tid]; }
    S->w2s[tid] = w2[tid];
    for (int i = tid; i < 1440; i += 256) ((float*)S->aggT)[i] = 0.f;
    __syncthreads();

    const int e0 = b * EPG;
    const int4 s4 = ((const int4*)(ei + e0))[tid];
    const int4 d4 = ((const int4*)(ei + NEDGE + e0))[tid];
    float* agw = &S->aggT[w][0][0];
    const int sls[4] = {s4.x & 63, s4.y & 63, s4.z & 63, s4.w & 63};
    const int dls[4] = {d4.x & 63, d4.y & 63, d4.z & 63, d4.w & 63};
#pragma unroll
    for (int e = 0; e < 4; ++e) {
      const int dl = dls[e];
      const float xi = S->xs[dl];
      const float dx = S->xs[sls[e]] - xi;
#pragma unroll
      for (int j = 0; j < 4; ++j) {
        float h = fmaxf(fmaf(xi, S->w1s[j], fmaf(dx, S->w1s[4 + j], S->b1s[j])), 0.f);
        atomicAdd(&agw[j * 72 + dl], h);
      }
      atomicAdd(&agw[4 * 72 + dl], 1.0f);
    }
    __syncthreads();

    if (tid < 64) {
      const int n = tid;
      const float a0 = S->aggT[0][0][n] + S->aggT[1][0][n] + S->aggT[2][0][n] + S->aggT[3][0][n];
      const float a1 = S->aggT[0][1][n] + S->aggT[1][1][n] + S->aggT[2][1][n] + S->aggT[3][1][n];
      const float a2 = S->aggT[0][2][n] + S->aggT[1][2][n] + S->aggT[2][2][n] + S->aggT[3][2][n];
      const float a3v = S->aggT[0][3][n] + S->aggT[1][3][n] + S->aggT[2][3][n] + S->aggT[3][3][n];
      const float dg = S->aggT[0][4][n] + S->aggT[1][4][n] + S->aggT[2][4][n] + S->aggT[3][4][n];
      *(float4*)&S->aggC[n][0] = make_float4(a0, a1, a2, a3v);
      S->aggC[n][4] = dg;
    }
    __syncthreads();

    const int c = tid & 63, qq = tid >> 6;
    const float wc0 = S->w2s[c], wc1 = S->w2s[64 + c];
    const float wc2 = S->w2s[128 + c], wc3 = S->w2s[192 + c];
    const float b2c = S->b2s[c];
    float s = 0.f, ss = 0.f;
    for (int n = qq; n < 64; n += 4) {
      const float4 a = *(const float4*)&S->aggC[n][0];
      const float dg = S->aggC[n][4];
      float v = a.x * wc0 + a.y * wc1 + a.z * wc2 + a.w * wc3 + dg * b2c;
      ubuf0[(size_t)(((b << 6) + n) << 6) + c] = f2bf(v);
      s += v; ss += v * v;
    }
    S->rs[qq][c] = s; S->rss[qq][c] = ss;
    __syncthreads();
    if (tid < 64) {
      float* dst = stats1 + ((b & (REP - 1)) << 7);
      atomicAdd(&dst[tid], S->rs[0][tid] + S->rs[1][tid] + S->rs[2][tid] + S->rs[3][tid]);
      atomicAdd(&dst[64 + tid], S->rss[0][tid] + S->rss[1][tid] + S->rss[2][tid] + S->rss[3][tid]);
    }
  }
}

// ---------------------------------------------------------------------------
// k_convm: BN(replica stats)+ReLU -> bf16 Yt -> conv1d as MFMA GEMM
// (M=o, N=l, K=192) -> bf16 out [l][o] + replica stats. (R6-proven.)
// ---------------------------------------------------------------------------
__global__ __launch_bounds__(256, 4) void k_convm(
    const ushort* __restrict__ in, const float* __restrict__ stats_in,
    const float* __restrict__ gamma, const float* __restrict__ beta,
    const ushort* __restrict__ cwt, const float* __restrict__ cb,
    ushort* __restrict__ out, float* __restrict__ stats_out)
{
  __shared__ ushort As[64][200];
  __shared__ ushort Yt[66][72];
  __shared__ float aco[64], bco[64], cbs[64];
  __shared__ float ldsS[64], ldsSS[64];
  const int tid = threadIdx.x;
  const int b = blockIdx.x;

  if (tid < 64) {
    float sm = 0.f, sq = 0.f;
#pragma unroll 8
    for (int r = 0; r < REP; ++r) {
      sm += stats_in[(r << 7) + tid];
      sq += stats_in[(r << 7) + 64 + tid];
    }
    const float mean = sm * (1.0f / CNTF);
    const float var = sq * (1.0f / CNTF) - mean * mean;
    const float a = gamma[tid] * rsqrtf(var + EPSV);
    aco[tid] = a;
    bco[tid] = beta[tid] - mean * a;
    cbs[tid] = cb[tid];
    Yt[0][tid] = 0;
    Yt[65][tid] = 0;
  }
  {
    const ushort8* gw = (const ushort8*)cwt;
#pragma unroll
    for (int i = 0; i < 6; ++i) {
      const int e8 = (i << 8) + tid;
      const int o = e8 / 24, k8 = (e8 - o * 24) << 3;
      *(ushort8*)&As[o][k8] = gw[e8];
    }
  }
  __syncthreads();

  const size_t base = (size_t)b << 12;
  {
    const int lr = tid >> 2, p = (tid & 3) << 4;
    const ushort8 r0 = *(const ushort8*)&in[base + (lr << 6) + p];
    const ushort8 r1 = *(const ushort8*)&in[base + (lr << 6) + p + 8];
    ushort tmp[16];
#pragma unroll
    for (int j = 0; j < 8; ++j)
      tmp[j] = f2bf(fmaxf(fmaf(aco[p + j], bf2f(r0[j]), bco[p + j]), 0.f));
#pragma unroll
    for (int j = 0; j < 8; ++j)
      tmp[8 + j] = f2bf(fmaxf(fmaf(aco[p + 8 + j], bf2f(r1[j]), bco[p + 8 + j]), 0.f));
    *(ushort8*)&Yt[lr + 1][p] = *(ushort8*)&tmp[0];
    *(ushort8*)&Yt[lr + 1][p + 8] = *(ushort8*)&tmp[8];
  }
  __syncthreads();

  const int lane = tid & 63, w = tid >> 6;
  const int lm = lane & 15, q = lane >> 4;
  f32x4 acc[4];
#pragma unroll
  for (int nt = 0; nt < 4; ++nt) acc[nt] = (f32x4){0.f, 0.f, 0.f, 0.f};
#pragma unroll
  for (int kk = 0; kk < 3; ++kk) {
#pragma unroll
    for (int ks = 0; ks < 2; ++ks) {
      const short8 af = *(const short8*)&As[(w << 4) + lm][(kk << 6) + (ks << 5) + (q << 3)];
#pragma unroll
      for (int nt = 0; nt < 4; ++nt) {
        const short8 bfr = *(const short8*)&Yt[(nt << 4) + lm + kk][(ks << 5) + (q << 3)];
        acc[nt] = __builtin_amdgcn_mfma_f32_16x16x32_bf16(af, bfr, acc[nt], 0, 0, 0);
      }
    }
  }

  const int obase = (w << 4) + (q << 2);
  const float4 cb4 = *(const float4*)&cbs[obase];
  float s[4] = {0.f, 0.f, 0.f, 0.f}, ss[4] = {0.f, 0.f, 0.f, 0.f};
#pragma unroll
  for (int nt = 0; nt < 4; ++nt) {
    const int l = (nt << 4) + lm;
    float4 v = make_float4(acc[nt][0] + cb4.x, acc[nt][1] + cb4.y,
                           acc[nt][2] + cb4.z, acc[nt][3] + cb4.w);
    *(ushort4*)&out[base + (l << 6) + obase] =
        make_ushort4(f2bf(v.x), f2bf(v.y), f2bf(v.z), f2bf(v.w));
    s[0] += v.x; ss[0] += v.x * v.x;
    s[1] += v.y; ss[1] += v.y * v.y;
    s[2] += v.z; ss[2] += v.z * v.z;
    s[3] += v.w; ss[3] += v.w * v.w;
  }
#pragma unroll
  for (int i = 0; i < 4; ++i) {
#pragma unroll
    for (int off = 1; off < 16; off <<= 1) {
      s[i] += __shfl_xor(s[i], off);
      ss[i] += __shfl_xor(ss[i], off);
    }
    if (lm == 0) { ldsS[obase + i] = s[i]; ldsSS[obase + i] = ss[i]; }
  }
  __syncthreads();
  if (tid < 64) {
    float* dst = stats_out + ((b & (REP - 1)) << 7);
    atomicAdd(&dst[tid], ldsS[tid]);
    atomicAdd(&dst[64 + tid], ldsSS[tid]);
  }
}

// ---------------------------------------------------------------------------
// k_mlp1tail: mlp1 (grid 512 = 16 bx x 4 by x 8 bz; each block 8 K-chunks,
// acc[4]) writes its h1part slice, then increments tcnt[bx]. The 32nd
// arrival for bx runs the tail for bx's 64 graphs (4x 16-graph half-staged
// body, R7-proven). No grid barrier, no spinning.
// ---------------------------------------------------------------------------
__global__ __launch_bounds__(256, 4) void k_mlp1tail(
    const ushort* __restrict__ z3, const float* __restrict__ stats3,
    const float* __restrict__ g3, const float* __restrict__ be3,
    const ushort* __restrict__ wbf1t, float* __restrict__ h1part,
    int* __restrict__ tcnt,
    const float* __restrict__ bm1,
    const ushort* __restrict__ wbf2t, const float* __restrict__ bm2,
    const ushort* __restrict__ wbf3t, const float* __restrict__ bm3,
    const ushort* __restrict__ wptbf, const float* __restrict__ bp,
    float* __restrict__ out)
{
  __shared__ __align__(16) char smem[sizeof(SmemTailH)];
  __shared__ int isfin;
  const int tid = threadIdx.x;
  const int b = blockIdx.x;
  const int bx = b & 15, by = (b >> 4) & 3, bz = b >> 6;
  const int lane = tid & 63, w = tid >> 6;
  const int lm = lane & 15, q = lane >> 4;

  // ======== mlp1 part ========
  {
    SmemMlp1* S = (SmemMlp1*)smem;
    if (tid < 64) {
      float sm = 0.f, sq = 0.f;
#pragma unroll 8
      for (int r = 0; r < REP; ++r) {
        sm += stats3[(r << 7) + tid];
        sq += stats3[(r << 7) + 64 + tid];
      }
      const float mean = sm * (1.0f / CNTF);
      const float var = sq * (1.0f / CNTF) - mean * mean;
      const float a = g3[tid] * rsqrtf(var + EPSV);
      S->a3s[tid] = a;
      S->b3s[tid] = be3[tid] - mean * a;
    }
    __syncthreads();

    const int gy = tid >> 2, py = (tid & 3) << 4;
    const int g0 = bx << 6, n0 = by << 6;

    f32x4 acc[4];
#pragma unroll
    for (int nt = 0; nt < 4; ++nt) acc[nt] = (f32x4){0.f, 0.f, 0.f, 0.f};
    const size_t ybase = ((size_t)(g0 + gy) << 12);

#pragma unroll 1
    for (int ck = 0; ck < 8; ++ck) {
      const int kcg = (bz << 3) + ck;
      const int kc = kcg << 6;
      if (ck) __syncthreads();
      {
        const ushort* src = z3 + ybase + kc + py;
        const ushort8 r0 = *(const ushort8*)src;
        const ushort8 r1 = *(const ushort8*)(src + 8);
        ushort tmp[16];
#pragma unroll
        for (int j = 0; j < 8; ++j)
          tmp[j] = f2bf(fmaxf(fmaf(S->a3s[py + j], bf2f(r0[j]), S->b3s[py + j]), 0.f));
#pragma unroll
        for (int j = 0; j < 8; ++j)
          tmp[8 + j] = f2bf(fmaxf(fmaf(S->a3s[py + 8 + j], bf2f(r1[j]), S->b3s[py + 8 + j]), 0.f));
        *(ushort8*)&S->Ys[gy][py] = *(ushort8*)&tmp[0];
        *(ushort8*)&S->Ys[gy][py + 8] = *(ushort8*)&tmp[8];
      }
      {
        const ushort8* gw = (const ushort8*)(wbf1t + ((size_t)kcg << 14) + (n0 << 6));
        const int e8a = tid, e8b = tid + 256;
        *(ushort8*)&S->Ws[e8a >> 3][(e8a & 7) << 3] = gw[e8a];
        *(ushort8*)&S->Ws[e8b >> 3][(e8b & 7) << 3] = gw[e8b];
      }
      __syncthreads();
#pragma unroll
      for (int ks = 0; ks < 2; ++ks) {
        const short8 af = *(const short8*)&S->Ys[(w << 4) + lm][(ks << 5) + (q << 3)];
#pragma unroll
        for (int nt = 0; nt < 4; ++nt) {
          const short8 bfr = *(const short8*)&S->Ws[(nt << 4) + lm][(ks << 5) + (q << 3)];
          acc[nt] = __builtin_amdgcn_mfma_f32_16x16x32_bf16(af, bfr, acc[nt], 0, 0, 0);
        }
      }
    }

    float* dst0 = h1part + ((size_t)bz << 18);
    const int gout = g0 + (w << 4) + (q << 2);
#pragma unroll
    for (int nt = 0; nt < 4; ++nt) {
      const int col = n0 + (nt << 4) + lm;
#pragma unroll
      for (int i = 0; i < 4; ++i)
        dst0[((size_t)(gout + i) << 8) + col] = acc[nt][i];
    }
  }

  // ======== last-arrival promotion ========
  __syncthreads();
  if (tid == 0) {
    __threadfence();   // release own h1part stores (agent scope)
    const int r = __hip_atomic_fetch_add(tcnt + bx, 1, __ATOMIC_ACQ_REL,
                                         __HIP_MEMORY_SCOPE_AGENT);
    isfin = (r == 31);
    if (r == 31) __threadfence();   // acquire others' stores
  }
  __syncthreads();
  if (!isfin) return;

  // ======== tail for graphs bx*64 .. bx*64+63 (4 x 16-graph bodies) ========
  SmemTailH* T = (SmemTailH*)smem;
  ushort* wpt = &T->Ws[0][0];       // [16][264] view
  const int gr = q << 2;

#pragma unroll 1
  for (int t = 0; t < 4; ++t) {
    const int g0 = (bx << 6) + (t << 4);
    __syncthreads();                 // LDS reuse boundary

    // h1 = relu(sum of 8 partials + bm1) -> bf16
    {
      const int r = tid >> 4, c0 = (tid & 15) << 4;
      const float* srcb = h1part + ((size_t)(g0 + r) << 8) + c0;
#pragma unroll
      for (int i = 0; i < 4; ++i) {
        float4 vs = *(const float4*)(bm1 + c0 + (i << 2));
#pragma unroll
        for (int bzz = 0; bzz < 8; ++bzz) {
          const float4 p = *(const float4*)(srcb + ((size_t)bzz << 18) + (i << 2));
          vs.x += p.x; vs.y += p.y; vs.z += p.z; vs.w += p.w;
        }
        *(ushort4*)&T->h1s[r][c0 + (i << 2)] = make_ushort4(
            f2bf(fmaxf(vs.x, 0.f)), f2bf(fmaxf(vs.y, 0.f)),
            f2bf(fmaxf(vs.z, 0.f)), f2bf(fmaxf(vs.w, 0.f)));
      }
    }

    // ---- GEMM2 (half-staged Ws[128])
    f32x4 acc[4];
#pragma unroll
    for (int j = 0; j < 4; ++j) acc[j] = (f32x4){0.f, 0.f, 0.f, 0.f};
#pragma unroll 1
    for (int ck = 0; ck < 4; ++ck) {
#pragma unroll 1
      for (int h = 0; h < 2; ++h) {
        __syncthreads();
        {
          const ushort8* gw = (const ushort8*)(wbf2t + (ck << 14) + (h << 13));
#pragma unroll
          for (int i = 0; i < 4; ++i) {
            const int e8 = (i << 8) + tid;
            *(ushort8*)&T->Ws[e8 >> 3][(e8 & 7) << 3] = gw[e8];
          }
        }
        __syncthreads();
#pragma unroll
        for (int ks = 0; ks < 2; ++ks) {
          const short8 af = *(const short8*)&T->h1s[lm][(ck << 6) + (ks << 5) + (q << 3)];
#pragma unroll
          for (int nt = 0; nt < 2; ++nt) {
            const short8 bfr = *(const short8*)&T->Ws[(w << 5) + (nt << 4) + lm][(ks << 5) + (q << 3)];
            acc[(h << 1) + nt] = __builtin_amdgcn_mfma_f32_16x16x32_bf16(af, bfr, acc[(h << 1) + nt], 0, 0, 0);
          }
        }
      }
    }
    __syncthreads();
#pragma unroll
    for (int j = 0; j < 4; ++j) {
      const int col = ((j >> 1) << 7) + (w << 5) + ((j & 1) << 4) + lm;
      const float bv = bm2[col];
#pragma unroll
      for (int i = 0; i < 4; ++i)
        T->h2s[gr + i][col] = f2bf(fmaxf(acc[j][i] + bv, 0.f));
    }

    // ---- GEMM3
    f32x4 acc2[4];
#pragma unroll
    for (int j = 0; j < 4; ++j) acc2[j] = (f32x4){0.f, 0.f, 0.f, 0.f};
#pragma unroll 1
    for (int ck = 0; ck < 4; ++ck) {
#pragma unroll 1
      for (int h = 0; h < 2; ++h) {
        __syncthreads();
        {
          const ushort8* gw = (const ushort8*)(wbf3t + (ck << 14) + (h << 13));
#pragma unroll
          for (int i = 0; i < 4; ++i) {
            const int e8 = (i << 8) + tid;
            *(ushort8*)&T->Ws[e8 >> 3][(e8 & 7) << 3] = gw[e8];
          }
        }
        __syncthreads();
#pragma unroll
        for (int ks = 0; ks < 2; ++ks) {
          const short8 af = *(const short8*)&T->h2s[lm][(ck << 6) + (ks << 5) + (q << 3)];
#pragma unroll
          for (int nt = 0; nt < 2; ++nt) {
            const short8 bfr = *(const short8*)&T->Ws[(w << 5) + (nt << 4) + lm][(ks << 5) + (q << 3)];
            acc2[(h << 1) + nt] = __builtin_amdgcn_mfma_f32_16x16x32_bf16(af, bfr, acc2[(h << 1) + nt], 0, 0, 0);
          }
        }
      }
    }

    __syncthreads();   // done reading h2s + Ws
    {
      const ushort8* gw = (const ushort8*)wptbf;
#pragma unroll
      for (int i = 0; i < 2; ++i) {
        const int e8 = (i << 8) + tid;
        const int flat = e8 << 3;
        const int a = flat >> 8, kk = flat & 255;
        *(ushort8*)&wpt[a * 264 + kk] = gw[e8];
      }
    }
#pragma unroll
    for (int j = 0; j < 4; ++j) {
      const int col = ((j >> 1) << 7) + (w << 5) + ((j & 1) << 4) + lm;
      const float bv = bm3[col];
#pragma unroll
      for (int i = 0; i < 4; ++i)
        T->h2s[gr + i][col] = f2bf(fmaxf(acc2[j][i] + bv, 0.f));
    }
    __syncthreads();

    if (w == 0) {
      f32x4 lacc = (f32x4){0.f, 0.f, 0.f, 0.f};
#pragma unroll
      for (int ks = 0; ks < 8; ++ks) {
        const short8 af = *(const short8*)&T->h2s[lm][(ks << 5) + (q << 3)];
        const short8 bfr = *(const short8*)&wpt[lm * 264 + (ks << 5) + (q << 3)];
        lacc = __builtin_amdgcn_mfma_f32_16x16x32_bf16(af, bfr, lacc, 0, 0, 0);
      }
      const float bpv = bp[lm];
      float lg[4], mx[4], se[4];
#pragma unroll
      for (int i = 0; i < 4; ++i) {
        lg[i] = lacc[i] + bpv;
        float m = lg[i];
#pragma unroll
        for (int off = 1; off < 16; off <<= 1) m = fmaxf(m, __shfl_xor(m, off));
        mx[i] = m;
        float e = expf(lg[i] - m);
#pragma unroll
        for (int off = 1; off < 16; off <<= 1) e += __shfl_xor(e, off);
        se[i] = e;
      }
#pragma unroll
      for (int i = 0; i < 4; ++i)
        out[((g0 + gr + i) << 4) + lm] = (lg[i] - mx[i]) - logf(se[i]);
    }
  }
}

// ---------------------------------------------------------------------------
extern "C" void kernel_launch(void* const* d_in, const int* in_sizes, int n_in,
                              void* d_out, int out_size, void* d_ws, size_t ws_size,
                              hipStream_t stream)
{
  const float* x   = (const float*)d_in[0];
  const int*   ei  = (const int*)d_in[1];
  const float* w1  = (const float*)d_in[2];
  const float* b1  = (const float*)d_in[3];
  const float* w2  = (const float*)d_in[4];
  const float* b2  = (const float*)d_in[5];
  const float* c2w = (const float*)d_in[6];
  const float* c2b = (const float*)d_in[7];
  const float* c3w = (const float*)d_in[8];
  const float* c3b = (const float*)d_in[9];
  const float* g1  = (const float*)d_in[10];
  const float* be1 = (const float*)d_in[11];
  const float* g2  = (const float*)d_in[12];
  const float* be2 = (const float*)d_in[13];
  const float* g3  = (const float*)d_in[14];
  const float* be3 = (const float*)d_in[15];
  const float* wm1 = (const float*)d_in[16];
  const float* bm1 = (const float*)d_in[17];
  const float* wm2 = (const float*)d_in[18];
  const float* bm2 = (const float*)d_in[19];
  const float* wm3 = (const float*)d_in[20];
  const float* bm3 = (const float*)d_in[21];
  const float* wp  = (const float*)d_in[22];
  const float* bp  = (const float*)d_in[23];

  char* ws = (char*)d_ws;
  ushort* ubuf0 = (ushort*)ws;                          // 8 MiB bf16 out0->z3
  ushort* ubuf1 = (ushort*)(ws + ((size_t)8 << 20));    // 8 MiB bf16 z2
  float*  h1part = (float*)(ws + ((size_t)16 << 20));   // 8 MiB fp32 partials
  ushort* wbf1t = (ushort*)(ws + ((size_t)24 << 20));   // 2 MiB bf16 wm1^T
  ushort* wbf2t = (ushort*)(ws + ((size_t)26 << 20));               // 128 KiB
  ushort* wbf3t = (ushort*)(ws + ((size_t)26 << 20) + (128 << 10)); // 128 KiB
  ushort* wptbf = (ushort*)(ws + ((size_t)26 << 20) + (256 << 10)); // 8 KiB
  float* stats  = (float*)(ws + ((size_t)27 << 20));    // 48 KiB + counters
  float* stats1 = stats;
  float* stats2 = stats + REP * 128;
  float* stats3 = stats + 2 * REP * 128;
  int*   tcnt   = (int*)(stats + 3 * REP * 128);        // 16 ints
  ushort* cwt2 = (ushort*)d_out;          // d_out scratch, overwritten by tail
  ushort* cwt3 = (ushort*)d_out + 12288;

  hipMemsetAsync(stats, 0, 3 * REP * 128 * sizeof(float) + 16 * sizeof(int),
                 stream);
  k_edgeprep<<<dim3(1024), dim3(256), 0, stream>>>(
      x, ei, w1, b1, w2, b2, c2w, c3w, wm1, wm2, wm3, wp,
      ubuf0, wbf1t, wbf2t, wbf3t, wptbf, stats1, cwt2, cwt3);
  k_convm<<<dim3(1024), dim3(256), 0, stream>>>(
      ubuf0, stats1, g1, be1, cwt2, c2b, ubuf1, stats2);
  k_convm<<<dim3(1024), dim3(256), 0, stream>>>(
      ubuf1, stats2, g2, be2, cwt3, c3b, ubuf0, stats3);
  k_mlp1tail<<<dim3(512), dim3(256), 0, stream>>>(
      ubuf0, stats3, g3, be3, wbf1t, h1part, tcnt,
      bm1, wbf2t, bm2, wbf3t, bm3, wptbf, bp, (float*)d_out);
}